// Round 9
// baseline (246.944 us; speedup 1.0000x reference)
//
#include <hip/hip_runtime.h>
#include <math.h>

#define B_ 512
#define C_ 100
#define E_ 2048
#define F_ 128
#define NCHUNK 16
#define CHUNKW 128   // k-width per gram block

typedef _Float16 f16x8 __attribute__((ext_vector_type(8)));
typedef float    f32x4 __attribute__((ext_vector_type(4)));

#define AS1q __attribute__((address_space(1)))
#define AS3q __attribute__((address_space(3)))

// async global->LDS DMA, 16 B per lane; LDS dest = wave-uniform base + lane*16
__device__ __forceinline__ void gl_lds16(const void* g, void* lds_base) {
    __builtin_amdgcn_global_load_lds((const AS1q void*)g, (AS3q void*)lds_base, 16, 0, 0);
}

// Load an MFMA A/B fragment from a swizzled fp32 tile (128 rows x 64 floats):
// logical 16B-chunk g of row r lives at slot g^(r&15). Fragment (row r, pair p)
// = floats [p*8, p*8+8) = chunks p*2, p*2+1. Convert fp32->fp16 in registers.
__device__ __forceinline__ f16x8 frag_ld(const float* T, int r, int p) {
    const int k = r & 15;
    const int b = r << 6;
    const f32x4 lo = *(const f32x4*)&T[b + ((((p << 1))     ^ k) << 2)];
    const f32x4 hi = *(const f32x4*)&T[b + ((((p << 1) | 1) ^ k) << 2)];
    f16x8 fr;
    fr[0] = (_Float16)lo[0]; fr[1] = (_Float16)lo[1];
    fr[2] = (_Float16)lo[2]; fr[3] = (_Float16)lo[3];
    fr[4] = (_Float16)hi[0]; fr[5] = (_Float16)hi[1];
    fr[6] = (_Float16)hi[2]; fr[7] = (_Float16)hi[3];
    return fr;
}

// ---------------- kernel 1: per-class Gram-chunk from fp32 W directly
// grid (16 chunks, C_), block 256 = 4 waves (2x2). k-window = chunk*128 +: 128.
// y_chunk = G_chunk * u stored to ychunks[chunk][c][:]  (no atomics, no memset).
__global__ __launch_bounds__(256, 3)
void k_gram(const float* __restrict__ W, const float* __restrict__ u,
            float* __restrict__ ychunks) {
    const int chunk = blockIdx.x;
    const int c     = blockIdx.y;
    const int t  = threadIdx.x;
    const int w  = t >> 6;
    const int l  = t & 63;
    const int wm = w & 1, wn = w >> 1;
    const int ln = l & 15, quad = l >> 4;

    __shared__ float Ts[128 * 64];   // 32 KB fp32 tile

    f32x4 acc[4][4];
#pragma unroll
    for (int mt = 0; mt < 4; ++mt)
#pragma unroll
        for (int nt = 0; nt < 4; ++nt) acc[mt][nt] = (f32x4){0.f, 0.f, 0.f, 0.f};

    // DMA lane constants: instr q covers rows q*4..q*4+3; lane l -> row q*4+(l>>4),
    // row-chunk-slot cs=l&15 which must hold logical chunk cs^(r&15).
    const int lrow4 = l >> 4, cs = l & 15;
    const float* wbase = W + (size_t)c * F_ * E_ + chunk * CHUNKW;

#pragma unroll
    for (int it = 0; it < CHUNKW / 64; ++it) {
        const int k0 = it * 64;
#pragma unroll
        for (int qq = 0; qq < 8; ++qq) {
            const int q   = w * 8 + qq;
            const int r   = q * 4 + lrow4;
            const int off = ((cs ^ (r & 15)) << 2);
            gl_lds16(wbase + (size_t)r * E_ + k0 + off, &Ts[q * 256]);
        }
        __syncthreads();

#pragma unroll
        for (int kk = 0; kk < 64; kk += 32) {
            const int pb = quad + (kk >> 3);
            f16x8 av[4], bv[4];
#pragma unroll
            for (int mt = 0; mt < 4; ++mt)
                av[mt] = frag_ld(Ts, wm * 64 + mt * 16 + ln, pb);
#pragma unroll
            for (int nt = 0; nt < 4; ++nt)
                bv[nt] = frag_ld(Ts, wn * 64 + nt * 16 + ln, pb);
#pragma unroll
            for (int mt = 0; mt < 4; ++mt)
#pragma unroll
                for (int nt = 0; nt < 4; ++nt)
                    acc[mt][nt] = __builtin_amdgcn_mfma_f32_16x16x32_f16(
                        av[mt], bv[nt], acc[mt][nt], 0, 0, 0);
        }
        __syncthreads();
    }

    // y_chunk = G_chunk * u ; combine the two wn-halves via LDS, plain store
    const float* uc = u + (size_t)c * F_;
    float un[4];
#pragma unroll
    for (int nt = 0; nt < 4; ++nt) un[nt] = uc[wn * 64 + nt * 16 + ln];

    float* red = (float*)&Ts[0];        // [128][2] floats (post-barrier reuse)

#pragma unroll
    for (int mt = 0; mt < 4; ++mt) {
#pragma unroll
        for (int rr = 0; rr < 4; ++rr) {
            float py = acc[mt][0][rr] * un[0];
            py = fmaf(acc[mt][1][rr], un[1], py);
            py = fmaf(acc[mt][2][rr], un[2], py);
            py = fmaf(acc[mt][3][rr], un[3], py);
            py += __shfl_xor(py, 1, 64);
            py += __shfl_xor(py, 2, 64);
            py += __shfl_xor(py, 4, 64);
            py += __shfl_xor(py, 8, 64);
            if (ln == 0) {
                int m = wm * 64 + mt * 16 + quad * 4 + rr;
                red[m * 2 + wn] = py;
            }
        }
    }
    __syncthreads();
    if (t < 128) {
        float yv = red[t * 2] + red[t * 2 + 1];
        ychunks[((size_t)chunk * C_ + c) * F_ + t] = yv;
    }
}

// ---------------- kernel 2: fused MFMA GEMM + dist2 + exp from fp32 x, W
// grid (4 b-tiles, 100 classes), block 256 = 4 waves (2x2); M=128, N=128, BK=64.
__global__ __launch_bounds__(256, 2)
void k_main(const float* __restrict__ x, const float* __restrict__ W,
            const float* __restrict__ bias, const float* __restrict__ cent,
            const float* __restrict__ u, const float* __restrict__ ychunks,
            float* __restrict__ out) {
    const int c  = blockIdx.y;
    const int b0 = blockIdx.x * 128;
    const int t  = threadIdx.x;
    const int w  = t >> 6;
    const int l  = t & 63;
    const int wm = w & 1, wn = w >> 1;
    const int ln = l & 15, quad = l >> 4;

    __shared__ float Xs[128 * 64];   // 32 KB
    __shared__ float Ws[128 * 64];   // 32 KB
    __shared__ float red2[2][2];
    __shared__ float s_rsig;

    // ---- inline rsig = sqrt(u.y / y.y),  y[f] = sum_chunk ychunks[chunk][c][f]
    if (t < 128) {
        float yf = 0.f;
#pragma unroll
        for (int ch = 0; ch < NCHUNK; ++ch)
            yf += ychunks[((size_t)ch * C_ + c) * F_ + t];
        float nvp = u[(size_t)c * F_ + t] * yf;
        float tsp = yf * yf;
        for (int off = 32; off; off >>= 1) {
            nvp += __shfl_down(nvp, off, 64);
            tsp += __shfl_down(tsp, off, 64);
        }
        if (l == 0) { red2[w][0] = nvp; red2[w][1] = tsp; }
    }
    __syncthreads();
    if (t == 0) s_rsig = sqrtf((red2[0][0] + red2[1][0]) / (red2[0][1] + red2[1][1]));
    // s_rsig visibility guaranteed by the K-loop barriers below.

    f32x4 acc[4][4];
#pragma unroll
    for (int mt = 0; mt < 4; ++mt)
#pragma unroll
        for (int nt = 0; nt < 4; ++nt) acc[mt][nt] = (f32x4){0.f, 0.f, 0.f, 0.f};

    const int lrow4 = l >> 4, cs = l & 15;
    const float* xbase = x + (size_t)b0 * E_;
    const float* wbase = W + (size_t)c * F_ * E_;

    for (int k0 = 0; k0 < E_; k0 += 64) {
#pragma unroll
        for (int qq = 0; qq < 8; ++qq) {
            const int q   = w * 8 + qq;
            const int r   = q * 4 + lrow4;
            const int off = ((cs ^ (r & 15)) << 2);
            gl_lds16(xbase + (size_t)r * E_ + k0 + off, &Xs[q * 256]);
            gl_lds16(wbase + (size_t)r * E_ + k0 + off, &Ws[q * 256]);
        }
        __syncthreads();

#pragma unroll
        for (int kk = 0; kk < 64; kk += 32) {
            const int pb = quad + (kk >> 3);
            f16x8 av[4], bv[4];
#pragma unroll
            for (int mt = 0; mt < 4; ++mt)
                av[mt] = frag_ld(Xs, wm * 64 + mt * 16 + ln, pb);
#pragma unroll
            for (int nt = 0; nt < 4; ++nt)
                bv[nt] = frag_ld(Ws, wn * 64 + nt * 16 + ln, pb);
#pragma unroll
            for (int mt = 0; mt < 4; ++mt)
#pragma unroll
                for (int nt = 0; nt < 4; ++nt)
                    acc[mt][nt] = __builtin_amdgcn_mfma_f32_16x16x32_f16(
                        av[mt], bv[nt], acc[mt][nt], 0, 0, 0);
        }
        __syncthreads();
    }

    const float rsigma = s_rsig;

    float bi[4], ce[4];
#pragma unroll
    for (int nt = 0; nt < 4; ++nt) {
        int f = wn * 64 + nt * 16 + ln;
        bi[nt] = bias[c * F_ + f];
        ce[nt] = cent[c * F_ + f];
    }

    float* red = (float*)&Xs[0];        // [128][2] floats, post-barrier reuse

#pragma unroll
    for (int mt = 0; mt < 4; ++mt) {
#pragma unroll
        for (int r = 0; r < 4; ++r) {
            float part = 0.f;
#pragma unroll
            for (int nt = 0; nt < 4; ++nt) {
                float z = fmaf(acc[mt][nt][r], rsigma, bi[nt]);
                float d = ce[nt] - z;
                part = fmaf(d, d, part);
            }
            part += __shfl_xor(part, 1, 64);
            part += __shfl_xor(part, 2, 64);
            part += __shfl_xor(part, 4, 64);
            part += __shfl_xor(part, 8, 64);
            if (ln == 0) {
                int m = wm * 64 + mt * 16 + quad * 4 + r;
                red[m * 2 + wn] = part;
            }
        }
    }
    __syncthreads();
    if (t < 128) {
        float d2 = red[t * 2] + red[t * 2 + 1];
        out[(size_t)(b0 + t) * C_ + c] = expf(-0.5f * d2);
    }
}

extern "C" void kernel_launch(void* const* d_in, const int* in_sizes, int n_in,
                              void* d_out, int out_size, void* d_ws, size_t ws_size,
                              hipStream_t stream) {
    const float* x  = (const float*)d_in[0];
    const float* W  = (const float*)d_in[1];
    const float* b  = (const float*)d_in[2];
    const float* u  = (const float*)d_in[3];
    const float* cc = (const float*)d_in[4];
    float* out = (float*)d_out;

    float* ychunks = (float*)d_ws;      // NCHUNK*C_*F_ floats = 819,200 B

    dim3 ggrid(NCHUNK, C_);
    k_gram<<<ggrid, 256, 0, stream>>>(W, u, ychunks);

    dim3 grid(B_ / 128, C_);
    k_main<<<grid, 256, 0, stream>>>(x, W, b, cc, u, ychunks, out);
}

// Round 10
// 216.552 us; speedup vs baseline: 1.1403x; 1.1403x over previous
//
#include <hip/hip_runtime.h>
#include <math.h>

#define B_ 512
#define C_ 100
#define E_ 2048
#define F_ 128
#define NCHUNK 16
#define CHUNKW 128   // k-width per gram block

typedef _Float16 f16x8 __attribute__((ext_vector_type(8)));
typedef float    f32x4 __attribute__((ext_vector_type(4)));

#define AS1q __attribute__((address_space(1)))
#define AS3q __attribute__((address_space(3)))

// async global->LDS DMA, 16 B per lane; LDS dest = wave-uniform base + lane*16
__device__ __forceinline__ void gl_lds16(const void* g, void* lds_base) {
    __builtin_amdgcn_global_load_lds((const AS1q void*)g, (AS3q void*)lds_base, 16, 0, 0);
}

// Load an MFMA A/B fragment from a swizzled fp32 tile (128 rows x 64 floats):
// logical 16B-chunk g of row r lives at slot g^(r&15). Fragment (row r, pair p)
// = floats [p*8, p*8+8) = chunks p*2, p*2+1. Convert fp32->fp16 in registers.
__device__ __forceinline__ f16x8 frag_ld(const float* T, int r, int p) {
    const int k = r & 15;
    const int b = r << 6;
    const f32x4 lo = *(const f32x4*)&T[b + ((((p << 1))     ^ k) << 2)];
    const f32x4 hi = *(const f32x4*)&T[b + ((((p << 1) | 1) ^ k) << 2)];
    f16x8 fr;
    fr[0] = (_Float16)lo[0]; fr[1] = (_Float16)lo[1];
    fr[2] = (_Float16)lo[2]; fr[3] = (_Float16)lo[3];
    fr[4] = (_Float16)hi[0]; fr[5] = (_Float16)hi[1];
    fr[6] = (_Float16)hi[2]; fr[7] = (_Float16)hi[3];
    return fr;
}

// ---------------- kernel 1: Gram-chunk from fp32 W + Wh/xh production
// blocks 0..1599: (c = b>>4, chunk = b&15), k-window = chunk*128 +: 128.
//   fp32 W --DMA--> LDS (swizzled) --> {Gram MFMA (frag cvt)} and
//   {ds_read -> cvt -> Wh fp16 global store}.  y_chunk -> ychunks (no atomics).
// blocks 1600..1631: x fp32 -> fp16 xh.
__global__ __launch_bounds__(256, 3)
void k_gram(const float* __restrict__ W, _Float16* __restrict__ Wh,
            const float* __restrict__ x, _Float16* __restrict__ xh,
            const float* __restrict__ u, float* __restrict__ ychunks) {
    const int b = blockIdx.x;
    const int t = threadIdx.x;

    if (b >= 1600) {   // ---- x conversion
        const size_t base = (size_t)(b - 1600) * 32768 + t * 8;
#pragma unroll
        for (int it = 0; it < 16; ++it) {
            const size_t idx = base + (size_t)it * 2048;
            float4 a  = *(const float4*)(x + idx);
            float4 bb = *(const float4*)(x + idx + 4);
            f16x8 h;
            h[0] = (_Float16)a.x;  h[1] = (_Float16)a.y;  h[2] = (_Float16)a.z;  h[3] = (_Float16)a.w;
            h[4] = (_Float16)bb.x; h[5] = (_Float16)bb.y; h[6] = (_Float16)bb.z; h[7] = (_Float16)bb.w;
            *(f16x8*)(xh + idx) = h;
        }
        return;
    }

    const int c     = b >> 4;
    const int chunk = b & 15;
    const int w  = t >> 6;
    const int l  = t & 63;
    const int wm = w & 1, wn = w >> 1;
    const int ln = l & 15, quad = l >> 4;

    __shared__ float Ts[128 * 64];   // 32 KB fp32 tile

    f32x4 acc[4][4];
#pragma unroll
    for (int mt = 0; mt < 4; ++mt)
#pragma unroll
        for (int nt = 0; nt < 4; ++nt) acc[mt][nt] = (f32x4){0.f, 0.f, 0.f, 0.f};

    const int lrow4 = l >> 4, cs = l & 15;
    const float* wbase = W + (size_t)c * F_ * E_ + chunk * CHUNKW;

    // conversion-side constants: thread owns row cr, floats [cb, cb+32)
    const int cr = t >> 1, cb = (t & 1) * 32;
    _Float16* wdst = Wh + ((size_t)c * F_ + cr) * E_ + chunk * CHUNKW + cb;

#pragma unroll
    for (int it = 0; it < CHUNKW / 64; ++it) {
        const int k0 = it * 64;
#pragma unroll
        for (int qq = 0; qq < 8; ++qq) {
            const int q   = w * 8 + qq;
            const int r   = q * 4 + lrow4;
            const int off = ((cs ^ (r & 15)) << 2);
            gl_lds16(wbase + (size_t)r * E_ + k0 + off, &Ts[q * 256]);
        }
        __syncthreads();

        // ---- Wh production: LDS fp32 -> fp16 -> global (drains under MFMA)
        {
            f32x4 v[8];
#pragma unroll
            for (int j = 0; j < 8; ++j) {
                const int g = (cb >> 2) + j;
                v[j] = *(const f32x4*)&Ts[cr * 64 + ((g ^ (cr & 15)) << 2)];
            }
#pragma unroll
            for (int j = 0; j < 4; ++j) {
                f16x8 h;
                h[0] = (_Float16)v[2*j][0]; h[1] = (_Float16)v[2*j][1];
                h[2] = (_Float16)v[2*j][2]; h[3] = (_Float16)v[2*j][3];
                h[4] = (_Float16)v[2*j+1][0]; h[5] = (_Float16)v[2*j+1][1];
                h[6] = (_Float16)v[2*j+1][2]; h[7] = (_Float16)v[2*j+1][3];
                *(f16x8*)(wdst + k0 + j * 8) = h;
            }
        }

        // ---- Gram MFMA phase
#pragma unroll
        for (int kk = 0; kk < 64; kk += 32) {
            const int pb = quad + (kk >> 3);
            f16x8 av[4], bv[4];
#pragma unroll
            for (int mt = 0; mt < 4; ++mt)
                av[mt] = frag_ld(Ts, wm * 64 + mt * 16 + ln, pb);
#pragma unroll
            for (int nt = 0; nt < 4; ++nt)
                bv[nt] = frag_ld(Ts, wn * 64 + nt * 16 + ln, pb);
#pragma unroll
            for (int mt = 0; mt < 4; ++mt)
#pragma unroll
                for (int nt = 0; nt < 4; ++nt)
                    acc[mt][nt] = __builtin_amdgcn_mfma_f32_16x16x32_f16(
                        av[mt], bv[nt], acc[mt][nt], 0, 0, 0);
        }
        __syncthreads();
    }

    // y_chunk = G_chunk * u ; combine the two wn-halves via LDS, plain store
    const float* uc = u + (size_t)c * F_;
    float un[4];
#pragma unroll
    for (int nt = 0; nt < 4; ++nt) un[nt] = uc[wn * 64 + nt * 16 + ln];

    float* red = (float*)&Ts[0];        // [128][2] floats (post-barrier reuse)

#pragma unroll
    for (int mt = 0; mt < 4; ++mt) {
#pragma unroll
        for (int rr = 0; rr < 4; ++rr) {
            float py = acc[mt][0][rr] * un[0];
            py = fmaf(acc[mt][1][rr], un[1], py);
            py = fmaf(acc[mt][2][rr], un[2], py);
            py = fmaf(acc[mt][3][rr], un[3], py);
            py += __shfl_xor(py, 1, 64);
            py += __shfl_xor(py, 2, 64);
            py += __shfl_xor(py, 4, 64);
            py += __shfl_xor(py, 8, 64);
            if (ln == 0) {
                int m = wm * 64 + mt * 16 + quad * 4 + rr;
                red[m * 2 + wn] = py;
            }
        }
    }
    __syncthreads();
    if (t < 128) {
        float yv = red[t * 2] + red[t * 2 + 1];
        ychunks[((size_t)chunk * C_ + c) * F_ + t] = yv;
    }
}

// ---------------- kernel 2: fused fp16 MFMA GEMM + dist2 + exp, rsig inline
// grid (4 b-tiles, 100 classes), block 256 = 4 waves (2x2); M=128, N=128, BK=64.
__global__ __launch_bounds__(256, 3)
void k_main(const _Float16* __restrict__ xh, const _Float16* __restrict__ Wh,
            const float* __restrict__ bias, const float* __restrict__ cent,
            const float* __restrict__ u, const float* __restrict__ ychunks,
            float* __restrict__ out) {
    const int c  = blockIdx.y;
    const int b0 = blockIdx.x * 128;
    const int t  = threadIdx.x;
    const int w  = t >> 6;
    const int l  = t & 63;
    const int wm = w & 1, wn = w >> 1;
    const int ln = l & 15, quad = l >> 4;

    __shared__ _Float16 Xs[128 * 64];   // 16 KB
    __shared__ _Float16 Ws[128 * 64];   // 16 KB
    __shared__ float red2[2][2];
    __shared__ float s_rsig;

    // ---- inline rsig = sqrt(u.y / y.y),  y[f] = sum_chunk ychunks[chunk][c][f]
    if (t < 128) {
        float yf = 0.f;
#pragma unroll
        for (int ch = 0; ch < NCHUNK; ++ch)
            yf += ychunks[((size_t)ch * C_ + c) * F_ + t];
        float nvp = u[(size_t)c * F_ + t] * yf;
        float tsp = yf * yf;
        for (int off = 32; off; off >>= 1) {
            nvp += __shfl_down(nvp, off, 64);
            tsp += __shfl_down(tsp, off, 64);
        }
        if (l == 0) { red2[w][0] = nvp; red2[w][1] = tsp; }
    }
    __syncthreads();
    if (t == 0) s_rsig = sqrtf((red2[0][0] + red2[1][0]) / (red2[0][1] + red2[1][1]));
    // s_rsig visibility guaranteed by the K-loop barriers below.

    f32x4 acc[4][4];
#pragma unroll
    for (int mt = 0; mt < 4; ++mt)
#pragma unroll
        for (int nt = 0; nt < 4; ++nt) acc[mt][nt] = (f32x4){0.f, 0.f, 0.f, 0.f};

    const int lr = l >> 3;
    const int lg = (l & 7) ^ lr;
    // wave w stages X rows [w*32,+32) and W rows [w*32,+32), 4 DMA instrs each
    const _Float16* xsrc = xh + (size_t)(b0 + w * 32 + lr) * E_ + lg * 8;
    const _Float16* wsrc = Wh + ((size_t)c * F_ + w * 32 + lr) * E_ + lg * 8;

    for (int k0 = 0; k0 < E_; k0 += 64) {
#pragma unroll
        for (int q = 0; q < 4; ++q)
            gl_lds16(xsrc + (size_t)q * 8 * E_ + k0, &Xs[(w * 4 + q) * 512]);
#pragma unroll
        for (int q = 0; q < 4; ++q)
            gl_lds16(wsrc + (size_t)q * 8 * E_ + k0, &Ws[(w * 4 + q) * 512]);
        __syncthreads();

#pragma unroll
        for (int kk = 0; kk < 64; kk += 32) {
            const int g0 = (kk >> 3) + quad;
            const int sw = (g0 ^ (ln & 7)) * 8;
            f16x8 av[4], bv[4];
#pragma unroll
            for (int mt = 0; mt < 4; ++mt)
                av[mt] = *(const f16x8*)&Xs[(wm * 64 + mt * 16 + ln) * 64 + sw];
#pragma unroll
            for (int nt = 0; nt < 4; ++nt)
                bv[nt] = *(const f16x8*)&Ws[(wn * 64 + nt * 16 + ln) * 64 + sw];
#pragma unroll
            for (int mt = 0; mt < 4; ++mt)
#pragma unroll
                for (int nt = 0; nt < 4; ++nt)
                    acc[mt][nt] = __builtin_amdgcn_mfma_f32_16x16x32_f16(
                        av[mt], bv[nt], acc[mt][nt], 0, 0, 0);
        }
        __syncthreads();
    }

    const float rsigma = s_rsig;

    float bi[4], ce[4];
#pragma unroll
    for (int nt = 0; nt < 4; ++nt) {
        int f = wn * 64 + nt * 16 + ln;
        bi[nt] = bias[c * F_ + f];
        ce[nt] = cent[c * F_ + f];
    }

    float* red = (float*)&Xs[0];        // [128][2] floats, post-barrier reuse

#pragma unroll
    for (int mt = 0; mt < 4; ++mt) {
#pragma unroll
        for (int r = 0; r < 4; ++r) {
            float part = 0.f;
#pragma unroll
            for (int nt = 0; nt < 4; ++nt) {
                float z = fmaf(acc[mt][nt][r], rsigma, bi[nt]);
                float d = ce[nt] - z;
                part = fmaf(d, d, part);
            }
            part += __shfl_xor(part, 1, 64);
            part += __shfl_xor(part, 2, 64);
            part += __shfl_xor(part, 4, 64);
            part += __shfl_xor(part, 8, 64);
            if (ln == 0) {
                int m = wm * 64 + mt * 16 + quad * 4 + r;
                red[m * 2 + wn] = part;
            }
        }
    }
    __syncthreads();
    if (t < 128) {
        float d2 = red[t * 2] + red[t * 2 + 1];
        out[(size_t)(b0 + t) * C_ + c] = expf(-0.5f * d2);
    }
}

extern "C" void kernel_launch(void* const* d_in, const int* in_sizes, int n_in,
                              void* d_out, int out_size, void* d_ws, size_t ws_size,
                              hipStream_t stream) {
    const float* x  = (const float*)d_in[0];
    const float* W  = (const float*)d_in[1];
    const float* b  = (const float*)d_in[2];
    const float* u  = (const float*)d_in[3];
    const float* cc = (const float*)d_in[4];
    float* out = (float*)d_out;

    // workspace layout (all 16B aligned)
    char* ws = (char*)d_ws;
    _Float16* Wh      = (_Float16*)ws;                                // 52,428,800 B
    _Float16* xh      = (_Float16*)(ws + (size_t)C_ * F_ * E_ * 2);   //  2,097,152 B
    float*    ychunks = (float*)(ws + (size_t)C_ * F_ * E_ * 2 + (size_t)B_ * E_ * 2); // 819,200 B

    k_gram<<<1632, 256, 0, stream>>>(W, Wh, x, xh, u, ychunks);

    dim3 grid(B_ / 128, C_);
    k_main<<<grid, 256, 0, stream>>>(xh, Wh, b, cc, u, ychunks, out);
}